// Round 14
// baseline (482.811 us; speedup 1.0000x reference)
//
#include <hip/hip_runtime.h>

typedef unsigned short u16;
typedef unsigned char u8;
typedef unsigned int u32;
typedef __bf16 bf16x8 __attribute__((ext_vector_type(8)));
typedef float f32x4 __attribute__((ext_vector_type(4)));
typedef float f32x2 __attribute__((ext_vector_type(2)));

#define NN 10000
#define EE 160000
#define MPAD 10112   // 79 * 128 = 158 * 64

__device__ inline float b2f(u16 u) { return __uint_as_float(((u32)u) << 16); }
__device__ inline u16 f2b(float f) {
    u32 u = __float_as_uint(f);
    return (u16)((u + 0x7fffu + ((u >> 16) & 1u)) >> 16);   // RNE
}
__device__ inline u8 f2f8(float v) {   // f32 -> OCP e4m3 (HW cvt)
    return (u8)(__builtin_amdgcn_cvt_pk_fp8_f32(v, v, 0, false) & 0xff);
}
__device__ inline float gelu_f(float x) {
    return 0.5f * x * (1.0f + erff(x * 0.70710678118654752f));
}
__device__ inline void load_lds16(const u16* g, u16* l) {
    __builtin_amdgcn_global_load_lds((const __attribute__((address_space(1))) u32*)g,
                                     (__attribute__((address_space(3))) u32*)l, 16, 0, 0);
}

// ---------------- CSR scan / fill ----------------
__global__ __launch_bounds__(256) void k_scan(const int* __restrict__ cnt, int* __restrict__ rowptr,
                                              int* __restrict__ cursor, float* __restrict__ dinv) {
    __shared__ int part[256];
    const int t = threadIdx.x;
    const int CH = 40;
    int base = t * CH;
    int ssum = 0;
    for (int k = 0; k < CH; k++) { int i = base + k; if (i < NN) ssum += cnt[i]; }
    part[t] = ssum;
    __syncthreads();
    for (int off = 1; off < 256; off <<= 1) {
        int v = (t >= off) ? part[t - off] : 0;
        __syncthreads();
        part[t] += v;
        __syncthreads();
    }
    int run = part[t] - ssum;
    for (int k = 0; k < CH; k++) {
        int i = base + k;
        if (i < NN) {
            rowptr[i] = run; cursor[i] = run;
            int c = cnt[i];
            dinv[i] = rsqrtf((float)(c + 1));
            run += c;
        }
    }
    if (t == 255) rowptr[NN] = run;
}

__global__ __launch_bounds__(256) void k_fill(const int* __restrict__ src, const int* __restrict__ dst,
                                              int* __restrict__ cursor, int* __restrict__ cols,
                                              float* __restrict__ vals, const float* __restrict__ dinv) {
    int e = blockIdx.x * 256 + threadIdx.x;
    if (e < EE) {
        int s = src[e], d = dst[e];
        int pos = atomicAdd(&cursor[d], 1);
        cols[pos] = s;
        vals[pos] = dinv[s] * dinv[d];
    }
}

// ---------------- mega ingest: transposes + padx + small-cvt + degree count ----------
struct TT { const float* src; u16* dst; int K, Nc, Kp; };
struct CvtSrcs { const float *b_in, *mh_b0, *mh_b12, *ln_g, *ln_b, *b1, *b2, *w3, *b3; };
__global__ __launch_bounds__(256) void k_ingest(TT t0, TT t1, TT t2, TT t3, TT t4,
                                                const float* __restrict__ x, u16* __restrict__ xp,
                                                CvtSrcs S, u16* __restrict__ smallC,
                                                const int* __restrict__ dstA, int* __restrict__ cnt) {
    int b = blockIdx.x;
    const int t = threadIdx.x;
    if (b < 656) {                       // LDS-tiled weight transpose
        TT T;
        if (b < 8)        { T = t0; }
        else if (b < 72)  { T = t1; b -= 8; }
        else if (b < 584) { T = t2; b -= 72; }
        else if (b < 648) { T = t3; b -= 584; }
        else              { T = t4; b -= 648; }
        int tk = (T.Kp + 63) >> 6, tn = T.Nc >> 6;
        int bb  = b / (tk * tn);
        int rem = b - bb * (tk * tn);
        int k0 = (rem / tn) * 64, n0 = (rem % tn) * 64;
        __shared__ u16 tile[64][65];
        const float* src = T.src + (size_t)bb * T.K * T.Nc;
        u16* dst = T.dst + (size_t)bb * T.Nc * T.Kp;
        int c = t & 63, r0 = t >> 6;
#pragma unroll
        for (int i = 0; i < 16; i++) {
            int r = r0 + i * 4;
            int k = k0 + r;
            u16 v = 0;
            if (k < T.K) v = f2b(src[(size_t)k * T.Nc + n0 + c]);
            tile[r][c] = v;
        }
        __syncthreads();
        int rr = t & 63, cc0 = t >> 6;
#pragma unroll
        for (int i = 0; i < 16; i++) {
            int cc = cc0 + i * 4;
            int k = k0 + rr;
            if (k < T.Kp) dst[(size_t)(n0 + cc) * T.Kp + k] = tile[rr][cc];
        }
    } else if (b < 5712) {               // pad x -> [MPAD][128] bf16
        int idx = (b - 656) * 256 + t;
        int r = idx >> 7, c = idx & 127;
        u16 v = 0;
        if (r < NN && c < 84) v = f2b(x[(size_t)r * 84 + c]);
        xp[idx] = v;
    } else if (b < 5752) {               // small tensors -> bf16
        int i = (b - 5712) * 256 + t;
        const float* s; int base;
        if (i < 256)       { s = S.b_in;   base = 0; }
        else if (i < 1280) { s = S.mh_b0;  base = 256; }
        else if (i < 3328) { s = S.mh_b12; base = 1280; }
        else if (i < 6400) { s = S.ln_g;   base = 3328; }
        else if (i < 9472) { s = S.ln_b;   base = 6400; }
        else if (i < 9728) { s = S.b1;     base = 9472; }
        else if (i < 9856) { s = S.b2;     base = 9728; }
        else if (i < 9984) { s = S.w3;     base = 9856; }
        else if (i < 9985) { s = S.b3;     base = 9984; }
        else return;
        smallC[i] = f2b(s[i - base]);
    } else {                             // degree count
        int e = (b - 5752) * 256 + t;
        if (e < EE) atomicAdd(&cnt[dstA[e]], 1);
    }
}

// ---------------- MFMA GEMM: ring-of-4 LDS slots (empirical best structure) --------
// One barrier per 64-K pair: drains DMAs issued a full compute-pair (~16 MFMAs) ago.
// K % 64 == 0. XCD-swizzled 1D grid. EPI 0: bf16 C=[gelu](acc+bias).
// EPI 2: col<256 -> concat bf16 stride 1024 (+bias); col>=256 -> Zb FP8 stride 768.
// EPI 3: fused final head — out[row] = sum_col gelu(acc+bias[col])*w3[col] + b3.
// BATCH: blockIdx.y selects A0..A3, offsets Bt/bias/col0 by z*256.
template<int TM, int TN, int ACT, int EPI, int BATCH>
__global__ __launch_bounds__(256) void k_gemm(const u16* __restrict__ A0, const u16* __restrict__ A1,
                                              const u16* __restrict__ A2, const u16* __restrict__ A3,
                                              const u16* __restrict__ Bt, const u16* __restrict__ bias,
                                              u16* __restrict__ C, u8* __restrict__ Z,
                                              const u16* __restrict__ w3c, const u16* __restrict__ b3c,
                                              float* __restrict__ fout,
                                              int K, int ldc, int col0, int NB_M, int NB_N) {
    constexpr int AM = TM / 32, AN = TN / 32;
    constexpr int CA = TM / 16, CB = TN / 16;
    constexpr int NCH = (CA + CB) / 4;
    constexpr int SLOT = (TM + TN) * 32;
    __shared__ __align__(16) u16 Sh[4][SLOT];
    __shared__ float shred[2][64];
    int id = blockIdx.x;
    int g8 = id & 7, sIdx = id >> 3;
    int nb = sIdx % NB_N, jb = sIdx / NB_N;
    int mb = g8 + 8 * jb;
    if (mb >= NB_M) return;
    const u16* A = A0;
    if (BATCH) {
        int z = blockIdx.y;
        if (z == 1) A = A1; else if (z == 2) A = A2; else if (z == 3) A = A3;
        Bt   += (size_t)z * 256 * K;
        bias += z * 256;
        col0 += z * 256;
    }
    const int t = threadIdx.x;
    const int wv = t >> 6, lane = t & 63;
    const int wm = wv >> 1, wn = wv & 1;
    const int quad = lane >> 4, l16 = lane & 15;
    const int tileM = mb * TM, tileN = nb * TN;

    f32x4 acc[AM][AN] = {};

    const int rch = lane >> 2, c8 = (lane & 3) * 8;
    const u16* gsrc[NCH];
    int lofs[NCH];
#pragma unroll
    for (int i = 0; i < NCH; i++) {
        int c = wv + 4 * i;
        if (c < CA) {
            gsrc[i] = A + (size_t)(tileM + c * 16 + rch) * K + c8;
            lofs[i] = c * 512 + lane * 8;
        } else {
            int cc = c - CA;
            gsrc[i] = Bt + (size_t)(tileN + cc * 16 + rch) * K + c8;
            lofs[i] = TM * 32 + cc * 512 + lane * 8;
        }
    }

#pragma unroll
    for (int i = 0; i < NCH; i++) load_lds16(gsrc[i], &Sh[0][lofs[i]]);
#pragma unroll
    for (int i = 0; i < NCH; i++) load_lds16(gsrc[i] + 32, &Sh[1][lofs[i]]);

    const int npair = K >> 6;
    for (int p = 0; p < npair; p++) {
        __syncthreads();   // drains pair-(p-1) DMAs (issued a full compute-pair ago)
        int cur = (p & 1) << 1;
        int nxt = cur ^ 2;
        int kc = p << 6;
        if (kc + 64 < K) {
#pragma unroll
            for (int i = 0; i < NCH; i++) load_lds16(gsrc[i] + kc + 64, &Sh[nxt][lofs[i]]);
#pragma unroll
            for (int i = 0; i < NCH; i++) load_lds16(gsrc[i] + kc + 96, &Sh[nxt + 1][lofs[i]]);
        }
#pragma unroll
        for (int h = 0; h < 2; h++) {
            const u16* Sb = Sh[cur + h];
            bf16x8 af[AM], bfr[AN];
#pragma unroll
            for (int tm = 0; tm < AM; tm++)
                af[tm] = *(const bf16x8*)&Sb[(wm * (TM / 2) + tm * 16 + l16) * 32 + quad * 8];
#pragma unroll
            for (int tn = 0; tn < AN; tn++)
                bfr[tn] = *(const bf16x8*)&Sb[TM * 32 + (wn * (TN / 2) + tn * 16 + l16) * 32 + quad * 8];
#pragma unroll
            for (int tm = 0; tm < AM; tm++)
#pragma unroll
                for (int tn = 0; tn < AN; tn++)
                    acc[tm][tn] = __builtin_amdgcn_mfma_f32_16x16x32_bf16(af[tm], bfr[tn], acc[tm][tn], 0, 0, 0);
        }
    }

    if (EPI == 3) {
        // fused final head: per (tm,r) reduce gelu(acc+b2)*w3 over this wave's cols,
        // then across l16 lanes, then across wn halves via LDS.
#pragma unroll
        for (int tm = 0; tm < AM; tm++)
#pragma unroll
            for (int r = 0; r < 4; r++) {
                float psum = 0.f;
#pragma unroll
                for (int tn = 0; tn < AN; tn++) {
                    int col = wn * (TN / 2) + tn * 16 + l16;
                    float v = gelu_f(acc[tm][tn][r] + b2f(bias[col]));
                    psum += v * b2f(w3c[col]);
                }
                for (int off = 8; off; off >>= 1) psum += __shfl_down(psum, off);
                if (l16 == 0) shred[wn][wm * (TM / 2) + tm * 16 + quad * 4 + r] = psum;
            }
        __syncthreads();
        if (t < TM) {
            int row = tileM + t;
            if (row < NN) fout[row] = shred[0][t] + shred[1][t] + b2f(b3c[0]);
        }
        return;
    }

#pragma unroll
    for (int tm = 0; tm < AM; tm++)
#pragma unroll
        for (int tn = 0; tn < AN; tn++)
#pragma unroll
            for (int r = 0; r < 4; r++) {
                int row = tileM + wm * (TM / 2) + tm * 16 + quad * 4 + r;
                int col = tileN + wn * (TN / 2) + tn * 16 + l16;
                float v = acc[tm][tn][r];
                if (EPI == 2) {
                    if (col < 256) C[(size_t)row * 1024 + col] = f2b(v + b2f(bias[col]));
                    else           Z[(size_t)row * 768 + (col - 256)] = f2f8(v);
                } else {
                    v += b2f(bias[col]);
                    if (ACT) v = gelu_f(v);
                    C[(size_t)row * ldc + col0 + col] = f2b(v);
                }
            }
}

// ---------------- unified propagation, g-major, 8 gathers in flight ----------------
// IN8: input fp8 e4m3 (W in bytes) else bf16 (W in elems). Output always bf16.
// g==0 && bias: -> concat [node][1024]+col0 with bias; else -> out2 stride OW at
// (g - (bias?1:0))*256.
__device__ inline void f8acc(uint2 u, float w, float* a) {
    f32x2 p0 = __builtin_amdgcn_cvt_pk_f32_fp8(u.x, false);
    f32x2 p1 = __builtin_amdgcn_cvt_pk_f32_fp8(u.x, true);
    f32x2 p2 = __builtin_amdgcn_cvt_pk_f32_fp8(u.y, false);
    f32x2 p3 = __builtin_amdgcn_cvt_pk_f32_fp8(u.y, true);
    a[0] += w * p0.x; a[1] += w * p0.y; a[2] += w * p1.x; a[3] += w * p1.y;
    a[4] += w * p2.x; a[5] += w * p2.y; a[6] += w * p3.x; a[7] += w * p3.y;
}
__device__ inline void bfacc(bf16x8 v, float w, float* a) {
#pragma unroll
    for (int i = 0; i < 8; i++) a[i] += w * (float)v[i];
}
template<int IN8>
__global__ __launch_bounds__(256) void k_prop(const void* __restrict__ hinv, int W, int G, int OW,
                                              const int* __restrict__ rowptr, const int* __restrict__ cols,
                                              const float* __restrict__ vals, const float* __restrict__ dinv,
                                              u16* __restrict__ concat, const u16* __restrict__ bias,
                                              int col0, u16* __restrict__ out2) {
    int unit = blockIdx.x * 4 + (threadIdx.x >> 6);
    if (unit >= NN * G) return;
    int g = unit / NN, node = unit - g * NN;
    int lane = threadIdx.x & 63;
    int half = lane >> 5, fl = lane & 31;
    const u8* base8 = (const u8*)hinv + g * 256 + fl * 8;
    const u16* baseb = (const u16*)hinv + g * 256 + fl * 8;
    float a[8] = {0, 0, 0, 0, 0, 0, 0, 0};
    if (half == 1) {    // self-loop on upper half (balances work)
        float sw = dinv[node] * dinv[node];
        if (IN8) f8acc(*(const uint2*)(base8 + (size_t)node * W), sw, a);
        else     bfacc(*(const bf16x8*)(baseb + (size_t)node * W), sw, a);
    }
    int s = rowptr[node], e = rowptr[node + 1];
    int q = s + half;
    for (; q + 14 < e; q += 16) {    // 8 gathers in flight per half-wave
        int j[8]; float w[8];
#pragma unroll
        for (int i = 0; i < 8; i++) { j[i] = cols[q + 2 * i]; w[i] = vals[q + 2 * i]; }
        if (IN8) {
            uint2 v[8];
#pragma unroll
            for (int i = 0; i < 8; i++) v[i] = *(const uint2*)(base8 + (size_t)j[i] * W);
#pragma unroll
            for (int i = 0; i < 8; i++) f8acc(v[i], w[i], a);
        } else {
            bf16x8 v[8];
#pragma unroll
            for (int i = 0; i < 8; i++) v[i] = *(const bf16x8*)(baseb + (size_t)j[i] * W);
#pragma unroll
            for (int i = 0; i < 8; i++) bfacc(v[i], w[i], a);
        }
    }
    for (; q + 2 < e; q += 4) {      // 2 in flight
        int j0 = cols[q], j1 = cols[q + 2];
        float w0 = vals[q], w1 = vals[q + 2];
        if (IN8) {
            uint2 v0 = *(const uint2*)(base8 + (size_t)j0 * W);
            uint2 v1 = *(const uint2*)(base8 + (size_t)j1 * W);
            f8acc(v0, w0, a); f8acc(v1, w1, a);
        } else {
            bf16x8 v0 = *(const bf16x8*)(baseb + (size_t)j0 * W);
            bf16x8 v1 = *(const bf16x8*)(baseb + (size_t)j1 * W);
            bfacc(v0, w0, a); bfacc(v1, w1, a);
        }
    }
    if (q < e) {
        if (IN8) f8acc(*(const uint2*)(base8 + (size_t)cols[q] * W), vals[q], a);
        else     bfacc(*(const bf16x8*)(baseb + (size_t)cols[q] * W), vals[q], a);
    }
#pragma unroll
    for (int i = 0; i < 8; i++) a[i] += __shfl_down(a[i], 32);
    if (half == 0) {
        int f = fl * 8;
        union { u16 u[8]; uint4 v; } pk;
        if (bias && g == 0) {
#pragma unroll
            for (int i = 0; i < 8; i++) pk.u[i] = f2b(a[i] + b2f(bias[f + i]));
            *(uint4*)(concat + (size_t)node * 1024 + col0 + f) = pk.v;
        } else {
#pragma unroll
            for (int i = 0; i < 8; i++) pk.u[i] = f2b(a[i]);
            int gg = g - (bias ? 1 : 0);
            *(uint4*)(out2 + (size_t)node * OW + gg * 256 + f) = pk.v;
        }
    }
}

// ---------------- LayerNorm(1024) + gelu, bf16 in -> bf16 out ----------------
__global__ __launch_bounds__(256) void k_ln_gelu(const u16* __restrict__ X, const u16* __restrict__ g,
                                                 const u16* __restrict__ b, u16* __restrict__ out) {
    __shared__ float red[256];
    const int row = blockIdx.x, t = threadIdx.x;
    ushort4 xv = *(const ushort4*)(X + (size_t)row * 1024 + t * 4);
    float x0 = b2f(xv.x), x1 = b2f(xv.y), x2 = b2f(xv.z), x3 = b2f(xv.w);
    red[t] = x0 + x1 + x2 + x3;
    __syncthreads();
    for (int off = 128; off; off >>= 1) {
        if (t < off) red[t] += red[t + off];
        __syncthreads();
    }
    float mu = red[0] * (1.f / 1024.f);
    __syncthreads();
    float d0 = x0 - mu, d1 = x1 - mu, d2 = x2 - mu, d3 = x3 - mu;
    red[t] = d0 * d0 + d1 * d1 + d2 * d2 + d3 * d3;
    __syncthreads();
    for (int off = 128; off; off >>= 1) {
        if (t < off) red[t] += red[t + off];
        __syncthreads();
    }
    float rs = rsqrtf(red[0] * (1.f / 1024.f) + 1e-5f);
    int c = t * 4;
    ushort4 gv = *(const ushort4*)(g + c);
    ushort4 bv = *(const ushort4*)(b + c);
    ushort4 o;
    o.x = f2b(gelu_f(d0 * rs * b2f(gv.x) + b2f(bv.x)));
    o.y = f2b(gelu_f(d1 * rs * b2f(gv.y) + b2f(bv.y)));
    o.z = f2b(gelu_f(d2 * rs * b2f(gv.z) + b2f(bv.z)));
    o.w = f2b(gelu_f(d3 * rs * b2f(gv.w) + b2f(bv.w)));
    *(ushort4*)(out + (size_t)row * 1024 + c) = o;
}

extern "C" void kernel_launch(void* const* d_in, const int* in_sizes, int n_in,
                              void* d_out, int out_size, void* d_ws, size_t ws_size,
                              hipStream_t stream) {
    (void)in_sizes; (void)n_in; (void)out_size; (void)ws_size;
    const float* x  = (const float*)d_in[0];
    const int*   ei = (const int*)d_in[1];
    float* out = (float*)d_out;

    char* p = (char*)d_ws;
    auto alloc = [&](size_t bytes) { char* q = p; p += (bytes + 255) & ~(size_t)255; return q; };
    int*   cnt    = (int*)alloc(NN * 4);
    int*   rowptr = (int*)alloc((NN + 1) * 4);
    int*   cursor = (int*)alloc(NN * 4);
    float* dinv   = (float*)alloc(NN * 4);
    int*   cols   = (int*)alloc(EE * 4);
    float* vals   = (float*)alloc(EE * 4);
    u16*   xp     = (u16*)alloc((size_t)MPAD * 128 * 2);
    u16*   wbuf   = (u16*)alloc((size_t)2686976 * 2);
    u16*   smallC = (u16*)alloc(10240 * 2);
    u16*   S1     = (u16*)alloc((size_t)MPAD * 256 * 2);
    u16*   S2     = (u16*)alloc((size_t)MPAD * 256 * 2);
    u16*   S3     = (u16*)alloc((size_t)MPAD * 256 * 2);
    u16*   S4     = (u16*)alloc((size_t)MPAD * 256 * 2);
    u8*    Zb     = (u8*)alloc((size_t)MPAD * 768);
    u16*   Y2     = (u16*)alloc((size_t)MPAD * 512 * 2);
    u16*   Y3     = (u16*)alloc((size_t)MPAD * 256 * 2);
    u16*   bufA   = (u16*)alloc((size_t)MPAD * 1024 * 2);
    u16*   concat = (u16*)alloc((size_t)MPAD * 1024 * 2);

    u16* winT  = wbuf;             // [256][128]
    u16* w0T   = wbuf + 32768;     // [4][256][256]
    u16* w12T  = wbuf + 294912;    // [8][256][1024]
    u16* w1T   = wbuf + 2392064;   // [256][1024]
    u16* w2T   = wbuf + 2654208;   // [128][256]
    u16* binC  = smallC;
    u16* mb0C  = smallC + 256;
    u16* mb12C = smallC + 1280;
    u16* lngC  = smallC + 3328;
    u16* lnbC  = smallC + 6400;
    u16* b1C   = smallC + 9472;
    u16* b2C   = smallC + 9728;
    u16* w3C   = smallC + 9856;
    u16* b3C   = smallC + 9984;

    const int* srcA = ei;
    const int* dstA = ei + EE;

    hipMemsetAsync(cnt, 0, NN * 4, stream);

    TT t0{(const float*)d_in[2],  winT, 84,   256, 128};
    TT t1{(const float*)d_in[4],  w0T,  256,  256, 256};
    TT t2{(const float*)d_in[6],  w12T, 1024, 256, 1024};
    TT t3{(const float*)d_in[10], w1T,  1024, 256, 1024};
    TT t4{(const float*)d_in[12], w2T,  256,  128, 256};
    CvtSrcs CS{(const float*)d_in[3], (const float*)d_in[5], (const float*)d_in[7],
               (const float*)d_in[8], (const float*)d_in[9], (const float*)d_in[11],
               (const float*)d_in[13], (const float*)d_in[14], (const float*)d_in[15]};
    k_ingest<<<6377, 256, 0, stream>>>(t0, t1, t2, t3, t4, x, xp, CS, smallC, dstA, cnt);

    k_scan<<<1, 256, 0, stream>>>(cnt, rowptr, cursor, dinv);
    k_fill<<<(EE + 255) / 256, 256, 0, stream>>>(srcA, dstA, cursor, cols, vals, dinv);

    auto gx = [](int nbm, int nbn) { return 8 * ((nbm + 7) / 8) * nbn; };

    // input GEMM: S1 = gelu(xp @ winT^T + b_in)  [MPAD,256], K=128
    k_gemm<128, 64, 1, 0, 0><<<gx(79, 4), 256, 0, stream>>>(xp, xp, xp, xp, winT, binC, S1, nullptr,
                                                            nullptr, nullptr, nullptr, 128, 256, 0, 79, 4);

    // ---- layer 0: prop chain (bf16) then batched GEMM ----
    k_prop<0><<<2500, 256, 0, stream>>>(S1, 256, 1, 256, rowptr, cols, vals, dinv, nullptr, nullptr, 0, S2);
    k_prop<0><<<2500, 256, 0, stream>>>(S2, 256, 1, 256, rowptr, cols, vals, dinv, nullptr, nullptr, 0, S3);
    k_prop<0><<<2500, 256, 0, stream>>>(S3, 256, 1, 256, rowptr, cols, vals, dinv, nullptr, nullptr, 0, S4);
    k_gemm<128, 64, 0, 0, 1><<<dim3(gx(79, 4), 4), 256, 0, stream>>>(S1, S2, S3, S4, w0T, mb0C, concat, nullptr,
                                                                     nullptr, nullptr, nullptr, 256, 1024, 0, 79, 4);
    k_ln_gelu<<<NN, 256, 0, stream>>>(concat, lngC, lnbC, bufA);

    // ---- layers 1,2: merged GEMM (EPI2: z -> fp8 Zb) + prop chain (single fp8 quant) ----
    for (int L = 0; L < 2; L++) {
        const u16* WT = w12T + (size_t)L * 1024 * 1024;
        const u16* BB = mb12C + L * 1024;
        k_gemm<128, 64, 0, 2, 0><<<gx(79, 16), 256, 0, stream>>>(bufA, bufA, bufA, bufA, WT, BB, concat, Zb,
                                                                 nullptr, nullptr, nullptr, 1024, 0, 0, 79, 16);
        // sweep1: fp8 in (768-wide); g0 -> concat col256 (+b1); g1,g2 -> Y2 bf16 [.,512]
        k_prop<1><<<7500, 256, 0, stream>>>(Zb, 768, 3, 512, rowptr, cols, vals, dinv, concat, BB + 256, 256, Y2);
        // sweep2: bf16 in; g0 -> concat col512 (+b2); g1 -> Y3 bf16 [.,256]
        k_prop<0><<<5000, 256, 0, stream>>>(Y2, 512, 2, 256, rowptr, cols, vals, dinv, concat, BB + 512, 512, Y3);
        // sweep3: bf16 in; -> concat col768 (+b3)
        k_prop<0><<<2500, 256, 0, stream>>>(Y3, 256, 1, 0, rowptr, cols, vals, dinv, concat, BB + 768, 768, nullptr);
        k_ln_gelu<<<NN, 256, 0, stream>>>(concat, lngC + (L + 1) * 1024, lnbC + (L + 1) * 1024, bufA);
    }

    // ---- final MLP: w1 GEMM, then fused w2-GEMM + head dot ----
    k_gemm<64, 64, 1, 0, 0><<<gx(158, 4), 256, 0, stream>>>(bufA, bufA, bufA, bufA, w1T, b1C, S1, nullptr,
                                                            nullptr, nullptr, nullptr, 1024, 256, 0, 158, 4);
    k_gemm<64, 128, 0, 3, 0><<<gx(158, 1), 256, 0, stream>>>(S1, S1, S1, S1, w2T, b2C, nullptr, nullptr,
                                                             w3C, b3C, out, 256, 0, 0, 158, 1);
}

// Round 15
// 452.975 us; speedup vs baseline: 1.0659x; 1.0659x over previous
//
#include <hip/hip_runtime.h>

typedef unsigned short u16;
typedef unsigned char u8;
typedef unsigned int u32;
typedef __bf16 bf16x8 __attribute__((ext_vector_type(8)));
typedef float f32x4 __attribute__((ext_vector_type(4)));
typedef float f32x2 __attribute__((ext_vector_type(2)));

#define NN 10000
#define EE 160000
#define MPAD 10112   // 79 * 128 = 158 * 64

__device__ inline float b2f(u16 u) { return __uint_as_float(((u32)u) << 16); }
__device__ inline u16 f2b(float f) {
    u32 u = __float_as_uint(f);
    return (u16)((u + 0x7fffu + ((u >> 16) & 1u)) >> 16);   // RNE
}
__device__ inline u8 f2f8(float v) {   // f32 -> OCP e4m3 (HW cvt)
    return (u8)(__builtin_amdgcn_cvt_pk_fp8_f32(v, v, 0, false) & 0xff);
}
__device__ inline float gelu_f(float x) {
    return 0.5f * x * (1.0f + erff(x * 0.70710678118654752f));
}
__device__ inline void load_lds16(const u16* g, u16* l) {
    __builtin_amdgcn_global_load_lds((const __attribute__((address_space(1))) u32*)g,
                                     (__attribute__((address_space(3))) u32*)l, 16, 0, 0);
}

// ---------------- CSR scan / fill ----------------
__global__ __launch_bounds__(256) void k_scan(const int* __restrict__ cnt, int* __restrict__ rowptr,
                                              int* __restrict__ cursor, float* __restrict__ dinv) {
    __shared__ int part[256];
    const int t = threadIdx.x;
    const int CH = 40;
    int base = t * CH;
    int ssum = 0;
    for (int k = 0; k < CH; k++) { int i = base + k; if (i < NN) ssum += cnt[i]; }
    part[t] = ssum;
    __syncthreads();
    for (int off = 1; off < 256; off <<= 1) {
        int v = (t >= off) ? part[t - off] : 0;
        __syncthreads();
        part[t] += v;
        __syncthreads();
    }
    int run = part[t] - ssum;
    for (int k = 0; k < CH; k++) {
        int i = base + k;
        if (i < NN) {
            rowptr[i] = run; cursor[i] = run;
            int c = cnt[i];
            dinv[i] = rsqrtf((float)(c + 1));
            run += c;
        }
    }
    if (t == 255) rowptr[NN] = run;
}

__global__ __launch_bounds__(256) void k_fill(const int* __restrict__ src, const int* __restrict__ dst,
                                              int* __restrict__ cursor, int* __restrict__ cols,
                                              float* __restrict__ vals, const float* __restrict__ dinv) {
    int e = blockIdx.x * 256 + threadIdx.x;
    if (e < EE) {
        int s = src[e], d = dst[e];
        int pos = atomicAdd(&cursor[d], 1);
        cols[pos] = s;
        vals[pos] = dinv[s] * dinv[d];
    }
}

// ---------------- mega ingest: transposes + padx + small-cvt + degree count ----------
struct TT { const float* src; u16* dst; int K, Nc, Kp; };
struct CvtSrcs { const float *b_in, *mh_b0, *mh_b12, *ln_g, *ln_b, *b1, *b2, *w3, *b3; };
__global__ __launch_bounds__(256) void k_ingest(TT t0, TT t1, TT t2, TT t3, TT t4,
                                                const float* __restrict__ x, u16* __restrict__ xp,
                                                CvtSrcs S, u16* __restrict__ smallC,
                                                const int* __restrict__ dstA, int* __restrict__ cnt) {
    int b = blockIdx.x;
    const int t = threadIdx.x;
    if (b < 656) {                       // LDS-tiled weight transpose
        TT T;
        if (b < 8)        { T = t0; }
        else if (b < 72)  { T = t1; b -= 8; }
        else if (b < 584) { T = t2; b -= 72; }
        else if (b < 648) { T = t3; b -= 584; }
        else              { T = t4; b -= 648; }
        int tk = (T.Kp + 63) >> 6, tn = T.Nc >> 6;
        int bb  = b / (tk * tn);
        int rem = b - bb * (tk * tn);
        int k0 = (rem / tn) * 64, n0 = (rem % tn) * 64;
        __shared__ u16 tile[64][65];
        const float* src = T.src + (size_t)bb * T.K * T.Nc;
        u16* dst = T.dst + (size_t)bb * T.Nc * T.Kp;
        int c = t & 63, r0 = t >> 6;
#pragma unroll
        for (int i = 0; i < 16; i++) {
            int r = r0 + i * 4;
            int k = k0 + r;
            u16 v = 0;
            if (k < T.K) v = f2b(src[(size_t)k * T.Nc + n0 + c]);
            tile[r][c] = v;
        }
        __syncthreads();
        int rr = t & 63, cc0 = t >> 6;
#pragma unroll
        for (int i = 0; i < 16; i++) {
            int cc = cc0 + i * 4;
            int k = k0 + rr;
            if (k < T.Kp) dst[(size_t)(n0 + cc) * T.Kp + k] = tile[rr][cc];
        }
    } else if (b < 5712) {               // pad x -> [MPAD][128] bf16
        int idx = (b - 656) * 256 + t;
        int r = idx >> 7, c = idx & 127;
        u16 v = 0;
        if (r < NN && c < 84) v = f2b(x[(size_t)r * 84 + c]);
        xp[idx] = v;
    } else if (b < 5752) {               // small tensors -> bf16
        int i = (b - 5712) * 256 + t;
        const float* s; int base;
        if (i < 256)       { s = S.b_in;   base = 0; }
        else if (i < 1280) { s = S.mh_b0;  base = 256; }
        else if (i < 3328) { s = S.mh_b12; base = 1280; }
        else if (i < 6400) { s = S.ln_g;   base = 3328; }
        else if (i < 9472) { s = S.ln_b;   base = 6400; }
        else if (i < 9728) { s = S.b1;     base = 9472; }
        else if (i < 9856) { s = S.b2;     base = 9728; }
        else if (i < 9984) { s = S.w3;     base = 9856; }
        else if (i < 9985) { s = S.b3;     base = 9984; }
        else return;
        smallC[i] = f2b(s[i - base]);
    } else {                             // degree count
        int e = (b - 5752) * 256 + t;
        if (e < EE) atomicAdd(&cnt[dstA[e]], 1);
    }
}

// ---------------- MFMA GEMM: ring-of-4 LDS slots (empirical best structure) --------
// One barrier per 64-K pair: drains DMAs issued a full compute-pair (~16 MFMAs) ago.
// K % 64 == 0. XCD-swizzled 1D grid. EPI 0: bf16 C=[gelu](acc+bias).
// EPI 2: col<256 -> concat bf16 stride 1024 (+bias); col>=256 -> Zb FP8 stride 768.
// EPI 3: fused final head — out[row] = sum_col gelu(acc+bias[col])*w3[col] + b3.
// BATCH: blockIdx.y selects A0..A3, offsets Bt/bias/col0 by z*256.
template<int TM, int TN, int ACT, int EPI, int BATCH>
__global__ __launch_bounds__(256) void k_gemm(const u16* __restrict__ A0, const u16* __restrict__ A1,
                                              const u16* __restrict__ A2, const u16* __restrict__ A3,
                                              const u16* __restrict__ Bt, const u16* __restrict__ bias,
                                              u16* __restrict__ C, u8* __restrict__ Z,
                                              const u16* __restrict__ w3c, const u16* __restrict__ b3c,
                                              float* __restrict__ fout,
                                              int K, int ldc, int col0, int NB_M, int NB_N) {
    constexpr int AM = TM / 32, AN = TN / 32;
    constexpr int CA = TM / 16, CB = TN / 16;
    constexpr int NCH = (CA + CB) / 4;
    constexpr int SLOT = (TM + TN) * 32;
    __shared__ __align__(16) u16 Sh[4][SLOT];
    __shared__ float shred[2][64];
    int id = blockIdx.x;
    int g8 = id & 7, sIdx = id >> 3;
    int nb = sIdx % NB_N, jb = sIdx / NB_N;
    int mb = g8 + 8 * jb;
    if (mb >= NB_M) return;
    const u16* A = A0;
    if (BATCH) {
        int z = blockIdx.y;
        if (z == 1) A = A1; else if (z == 2) A = A2; else if (z == 3) A = A3;
        Bt   += (size_t)z * 256 * K;
        bias += z * 256;
        col0 += z * 256;
    }
    const int t = threadIdx.x;
    const int wv = t >> 6, lane = t & 63;
    const int wm = wv >> 1, wn = wv & 1;
    const int quad = lane >> 4, l16 = lane & 15;
    const int tileM = mb * TM, tileN = nb * TN;

    f32x4 acc[AM][AN] = {};

    const int rch = lane >> 2, c8 = (lane & 3) * 8;
    const u16* gsrc[NCH];
    int lofs[NCH];
#pragma unroll
    for (int i = 0; i < NCH; i++) {
        int c = wv + 4 * i;
        if (c < CA) {
            gsrc[i] = A + (size_t)(tileM + c * 16 + rch) * K + c8;
            lofs[i] = c * 512 + lane * 8;
        } else {
            int cc = c - CA;
            gsrc[i] = Bt + (size_t)(tileN + cc * 16 + rch) * K + c8;
            lofs[i] = TM * 32 + cc * 512 + lane * 8;
        }
    }

#pragma unroll
    for (int i = 0; i < NCH; i++) load_lds16(gsrc[i], &Sh[0][lofs[i]]);
#pragma unroll
    for (int i = 0; i < NCH; i++) load_lds16(gsrc[i] + 32, &Sh[1][lofs[i]]);

    const int npair = K >> 6;
    for (int p = 0; p < npair; p++) {
        __syncthreads();   // drains pair-(p-1) DMAs (issued a full compute-pair ago)
        int cur = (p & 1) << 1;
        int nxt = cur ^ 2;
        int kc = p << 6;
        if (kc + 64 < K) {
#pragma unroll
            for (int i = 0; i < NCH; i++) load_lds16(gsrc[i] + kc + 64, &Sh[nxt][lofs[i]]);
#pragma unroll
            for (int i = 0; i < NCH; i++) load_lds16(gsrc[i] + kc + 96, &Sh[nxt + 1][lofs[i]]);
        }
#pragma unroll
        for (int h = 0; h < 2; h++) {
            const u16* Sb = Sh[cur + h];
            bf16x8 af[AM], bfr[AN];
#pragma unroll
            for (int tm = 0; tm < AM; tm++)
                af[tm] = *(const bf16x8*)&Sb[(wm * (TM / 2) + tm * 16 + l16) * 32 + quad * 8];
#pragma unroll
            for (int tn = 0; tn < AN; tn++)
                bfr[tn] = *(const bf16x8*)&Sb[TM * 32 + (wn * (TN / 2) + tn * 16 + l16) * 32 + quad * 8];
#pragma unroll
            for (int tm = 0; tm < AM; tm++)
#pragma unroll
                for (int tn = 0; tn < AN; tn++)
                    acc[tm][tn] = __builtin_amdgcn_mfma_f32_16x16x32_bf16(af[tm], bfr[tn], acc[tm][tn], 0, 0, 0);
        }
    }

    if (EPI == 3) {
#pragma unroll
        for (int tm = 0; tm < AM; tm++)
#pragma unroll
            for (int r = 0; r < 4; r++) {
                float psum = 0.f;
#pragma unroll
                for (int tn = 0; tn < AN; tn++) {
                    int col = wn * (TN / 2) + tn * 16 + l16;
                    float v = gelu_f(acc[tm][tn][r] + b2f(bias[col]));
                    psum += v * b2f(w3c[col]);
                }
                for (int off = 8; off; off >>= 1) psum += __shfl_down(psum, off);
                if (l16 == 0) shred[wn][wm * (TM / 2) + tm * 16 + quad * 4 + r] = psum;
            }
        __syncthreads();
        if (t < TM) {
            int row = tileM + t;
            if (row < NN) fout[row] = shred[0][t] + shred[1][t] + b2f(b3c[0]);
        }
        return;
    }

#pragma unroll
    for (int tm = 0; tm < AM; tm++)
#pragma unroll
        for (int tn = 0; tn < AN; tn++)
#pragma unroll
            for (int r = 0; r < 4; r++) {
                int row = tileM + wm * (TM / 2) + tm * 16 + quad * 4 + r;
                int col = tileN + wn * (TN / 2) + tn * 16 + l16;
                float v = acc[tm][tn][r];
                if (EPI == 2) {
                    if (col < 256) C[(size_t)row * 1024 + col] = f2b(v + b2f(bias[col]));
                    else           Z[(size_t)row * 768 + (col - 256)] = f2f8(v);
                } else {
                    v += b2f(bias[col]);
                    if (ACT) v = gelu_f(v);
                    C[(size_t)row * ldc + col0 + col] = f2b(v);
                }
            }
}

// ---------------- bf16 propagation, g-major, 4-deep ILP (L0 chain) ----------------
__global__ __launch_bounds__(256) void k_propw(const u16* __restrict__ hin, int W, int G,
                                               const int* __restrict__ rowptr, const int* __restrict__ cols,
                                               const float* __restrict__ vals, const float* __restrict__ dinv,
                                               u16* __restrict__ out2) {
    int unit = blockIdx.x * 4 + (threadIdx.x >> 6);
    if (unit >= NN * G) return;
    int g = unit / NN, node = unit - g * NN;
    int lane = threadIdx.x & 63;
    int half = lane >> 5, fl = lane & 31;
    const u16* base = hin + g * 256 + fl * 8;
    float a0 = 0, a1 = 0, a2 = 0, a3 = 0, a4 = 0, a5 = 0, a6 = 0, a7 = 0;
    if (half == 1) {
        float di = dinv[node], sw = di * di;
        bf16x8 sv = *(const bf16x8*)(base + (size_t)node * W);
        a0 = sw * (float)sv[0]; a1 = sw * (float)sv[1]; a2 = sw * (float)sv[2]; a3 = sw * (float)sv[3];
        a4 = sw * (float)sv[4]; a5 = sw * (float)sv[5]; a6 = sw * (float)sv[6]; a7 = sw * (float)sv[7];
    }
    int s = rowptr[node], e = rowptr[node + 1];
    int q = s + half;
    for (; q + 6 < e; q += 8) {
        int j0 = cols[q], j1 = cols[q + 2], j2 = cols[q + 4], j3 = cols[q + 6];
        float w0 = vals[q], w1 = vals[q + 2], w2 = vals[q + 4], w3 = vals[q + 6];
        bf16x8 v0 = *(const bf16x8*)(base + (size_t)j0 * W);
        bf16x8 v1 = *(const bf16x8*)(base + (size_t)j1 * W);
        bf16x8 v2 = *(const bf16x8*)(base + (size_t)j2 * W);
        bf16x8 v3 = *(const bf16x8*)(base + (size_t)j3 * W);
        a0 += w0 * (float)v0[0] + w1 * (float)v1[0] + w2 * (float)v2[0] + w3 * (float)v3[0];
        a1 += w0 * (float)v0[1] + w1 * (float)v1[1] + w2 * (float)v2[1] + w3 * (float)v3[1];
        a2 += w0 * (float)v0[2] + w1 * (float)v1[2] + w2 * (float)v2[2] + w3 * (float)v3[2];
        a3 += w0 * (float)v0[3] + w1 * (float)v1[3] + w2 * (float)v2[3] + w3 * (float)v3[3];
        a4 += w0 * (float)v0[4] + w1 * (float)v1[4] + w2 * (float)v2[4] + w3 * (float)v3[4];
        a5 += w0 * (float)v0[5] + w1 * (float)v1[5] + w2 * (float)v2[5] + w3 * (float)v3[5];
        a6 += w0 * (float)v0[6] + w1 * (float)v1[6] + w2 * (float)v2[6] + w3 * (float)v3[6];
        a7 += w0 * (float)v0[7] + w1 * (float)v1[7] + w2 * (float)v2[7] + w3 * (float)v3[7];
    }
    for (; q < e; q += 2) {
        int j = cols[q];
        float w = vals[q];
        bf16x8 v = *(const bf16x8*)(base + (size_t)j * W);
        a0 += w * (float)v[0]; a1 += w * (float)v[1]; a2 += w * (float)v[2]; a3 += w * (float)v[3];
        a4 += w * (float)v[4]; a5 += w * (float)v[5]; a6 += w * (float)v[6]; a7 += w * (float)v[7];
    }
    a0 += __shfl_down(a0, 32); a1 += __shfl_down(a1, 32);
    a2 += __shfl_down(a2, 32); a3 += __shfl_down(a3, 32);
    a4 += __shfl_down(a4, 32); a5 += __shfl_down(a5, 32);
    a6 += __shfl_down(a6, 32); a7 += __shfl_down(a7, 32);
    if (half == 0) {
        int f = fl * 8;
        union { u16 u[8]; uint4 v; } pk;
        pk.u[0] = f2b(a0); pk.u[1] = f2b(a1); pk.u[2] = f2b(a2); pk.u[3] = f2b(a3);
        pk.u[4] = f2b(a4); pk.u[5] = f2b(a5); pk.u[6] = f2b(a6); pk.u[7] = f2b(a7);
        *(uint4*)(out2 + (size_t)node * (size_t)(G * 256) + g * 256 + f) = pk.v;
    }
}

// ---------------- FP8 propagation, g-major, 4-deep ILP (layers 1/2 chains) --------
__device__ inline void f8acc(uint2 u, float w, float* a) {
    f32x2 p0 = __builtin_amdgcn_cvt_pk_f32_fp8(u.x, false);
    f32x2 p1 = __builtin_amdgcn_cvt_pk_f32_fp8(u.x, true);
    f32x2 p2 = __builtin_amdgcn_cvt_pk_f32_fp8(u.y, false);
    f32x2 p3 = __builtin_amdgcn_cvt_pk_f32_fp8(u.y, true);
    a[0] += w * p0.x; a[1] += w * p0.y; a[2] += w * p1.x; a[3] += w * p1.y;
    a[4] += w * p2.x; a[5] += w * p2.y; a[6] += w * p3.x; a[7] += w * p3.y;
}
__global__ __launch_bounds__(256) void k_propf8(const u8* __restrict__ hin, int W, int G,
                                                const int* __restrict__ rowptr, const int* __restrict__ cols,
                                                const float* __restrict__ vals, const float* __restrict__ dinv,
                                                u16* __restrict__ concat, const u16* __restrict__ bias,
                                                int col0, u8* __restrict__ out2) {
    int unit = blockIdx.x * 4 + (threadIdx.x >> 6);
    if (unit >= NN * G) return;
    int g = unit / NN, node = unit - g * NN;
    int lane = threadIdx.x & 63;
    int half = lane >> 5, fl = lane & 31;
    const u8* base = hin + g * 256 + fl * 8;
    float a[8] = {0, 0, 0, 0, 0, 0, 0, 0};
    if (half == 1) {
        float di = dinv[node];
        uint2 sv = *(const uint2*)(base + (size_t)node * W);
        f8acc(sv, di * di, a);
    }
    int s = rowptr[node], e = rowptr[node + 1];
    int q = s + half;
    for (; q + 6 < e; q += 8) {
        int j0 = cols[q], j1 = cols[q + 2], j2 = cols[q + 4], j3 = cols[q + 6];
        float w0 = vals[q], w1 = vals[q + 2], w2 = vals[q + 4], w3 = vals[q + 6];
        uint2 v0 = *(const uint2*)(base + (size_t)j0 * W);
        uint2 v1 = *(const uint2*)(base + (size_t)j1 * W);
        uint2 v2 = *(const uint2*)(base + (size_t)j2 * W);
        uint2 v3 = *(const uint2*)(base + (size_t)j3 * W);
        f8acc(v0, w0, a); f8acc(v1, w1, a); f8acc(v2, w2, a); f8acc(v3, w3, a);
    }
    for (; q < e; q += 2) {
        uint2 v = *(const uint2*)(base + (size_t)cols[q] * W);
        f8acc(v, vals[q], a);
    }
#pragma unroll
    for (int i = 0; i < 8; i++) a[i] += __shfl_down(a[i], 32);
    if (half == 0) {
        int f = fl * 8;
        if (g == 0) {
            union { u16 u[8]; uint4 v; } pk;
#pragma unroll
            for (int i = 0; i < 8; i++) pk.u[i] = f2b(a[i] + b2f(bias[f + i]));
            *(uint4*)(concat + (size_t)node * 1024 + col0 + f) = pk.v;
        } else {
            int W2 = W - 256;
            u32 lo = __builtin_amdgcn_cvt_pk_fp8_f32(a[0], a[1], 0, false);
            lo = __builtin_amdgcn_cvt_pk_fp8_f32(a[2], a[3], lo, true);
            u32 hi = __builtin_amdgcn_cvt_pk_fp8_f32(a[4], a[5], 0, false);
            hi = __builtin_amdgcn_cvt_pk_fp8_f32(a[6], a[7], hi, true);
            uint2 o; o.x = lo; o.y = hi;
            *(uint2*)(out2 + (size_t)node * W2 + (g - 1) * 256 + f) = o;
        }
    }
}

// ---------------- LayerNorm(1024) + gelu, bf16 in -> bf16 out ----------------
__global__ __launch_bounds__(256) void k_ln_gelu(const u16* __restrict__ X, const u16* __restrict__ g,
                                                 const u16* __restrict__ b, u16* __restrict__ out) {
    __shared__ float red[256];
    const int row = blockIdx.x, t = threadIdx.x;
    ushort4 xv = *(const ushort4*)(X + (size_t)row * 1024 + t * 4);
    float x0 = b2f(xv.x), x1 = b2f(xv.y), x2 = b2f(xv.z), x3 = b2f(xv.w);
    red[t] = x0 + x1 + x2 + x3;
    __syncthreads();
    for (int off = 128; off; off >>= 1) {
        if (t < off) red[t] += red[t + off];
        __syncthreads();
    }
    float mu = red[0] * (1.f / 1024.f);
    __syncthreads();
    float d0 = x0 - mu, d1 = x1 - mu, d2 = x2 - mu, d3 = x3 - mu;
    red[t] = d0 * d0 + d1 * d1 + d2 * d2 + d3 * d3;
    __syncthreads();
    for (int off = 128; off; off >>= 1) {
        if (t < off) red[t] += red[t + off];
        __syncthreads();
    }
    float rs = rsqrtf(red[0] * (1.f / 1024.f) + 1e-5f);
    int c = t * 4;
    ushort4 gv = *(const ushort4*)(g + c);
    ushort4 bv = *(const ushort4*)(b + c);
    ushort4 o;
    o.x = f2b(gelu_f(d0 * rs * b2f(gv.x) + b2f(bv.x)));
    o.y = f2b(gelu_f(d1 * rs * b2f(gv.y) + b2f(bv.y)));
    o.z = f2b(gelu_f(d2 * rs * b2f(gv.z) + b2f(bv.z)));
    o.w = f2b(gelu_f(d3 * rs * b2f(gv.w) + b2f(bv.w)));
    *(ushort4*)(out + (size_t)row * 1024 + c) = o;
}

extern "C" void kernel_launch(void* const* d_in, const int* in_sizes, int n_in,
                              void* d_out, int out_size, void* d_ws, size_t ws_size,
                              hipStream_t stream) {
    (void)in_sizes; (void)n_in; (void)out_size; (void)ws_size;
    const float* x  = (const float*)d_in[0];
    const int*   ei = (const int*)d_in[1];
    float* out = (float*)d_out;

    char* p = (char*)d_ws;
    auto alloc = [&](size_t bytes) { char* q = p; p += (bytes + 255) & ~(size_t)255; return q; };
    int*   cnt    = (int*)alloc(NN * 4);
    int*   rowptr = (int*)alloc((NN + 1) * 4);
    int*   cursor = (int*)alloc(NN * 4);
    float* dinv   = (float*)alloc(NN * 4);
    int*   cols   = (int*)alloc(EE * 4);
    float* vals   = (float*)alloc(EE * 4);
    u16*   xp     = (u16*)alloc((size_t)MPAD * 128 * 2);
    u16*   wbuf   = (u16*)alloc((size_t)2686976 * 2);
    u16*   smallC = (u16*)alloc(10240 * 2);
    u16*   S1     = (u16*)alloc((size_t)MPAD * 256 * 2);
    u16*   S2     = (u16*)alloc((size_t)MPAD * 256 * 2);
    u16*   S3     = (u16*)alloc((size_t)MPAD * 256 * 2);
    u16*   S4     = (u16*)alloc((size_t)MPAD * 256 * 2);
    u8*    Zb     = (u8*)alloc((size_t)MPAD * 768);
    u8*    Y2     = (u8*)alloc((size_t)MPAD * 512);
    u8*    Y3     = (u8*)alloc((size_t)MPAD * 256);
    u16*   bufA   = (u16*)alloc((size_t)MPAD * 1024 * 2);
    u16*   concat = (u16*)alloc((size_t)MPAD * 1024 * 2);

    u16* winT  = wbuf;             // [256][128]
    u16* w0T   = wbuf + 32768;     // [4][256][256]
    u16* w12T  = wbuf + 294912;    // [8][256][1024]
    u16* w1T   = wbuf + 2392064;   // [256][1024]
    u16* w2T   = wbuf + 2654208;   // [128][256]
    u16* binC  = smallC;
    u16* mb0C  = smallC + 256;
    u16* mb12C = smallC + 1280;
    u16* lngC  = smallC + 3328;
    u16* lnbC  = smallC + 6400;
    u16* b1C   = smallC + 9472;
    u16* b2C   = smallC + 9728;
    u16* w3C   = smallC + 9856;
    u16* b3C   = smallC + 9984;

    const int* srcA = ei;
    const int* dstA = ei + EE;

    hipMemsetAsync(cnt, 0, NN * 4, stream);

    TT t0{(const float*)d_in[2],  winT, 84,   256, 128};
    TT t1{(const float*)d_in[4],  w0T,  256,  256, 256};
    TT t2{(const float*)d_in[6],  w12T, 1024, 256, 1024};
    TT t3{(const float*)d_in[10], w1T,  1024, 256, 1024};
    TT t4{(const float*)d_in[12], w2T,  256,  128, 256};
    CvtSrcs CS{(const float*)d_in[3], (const float*)d_in[5], (const float*)d_in[7],
               (const float*)d_in[8], (const float*)d_in[9], (const float*)d_in[11],
               (const float*)d_in[13], (const float*)d_in[14], (const float*)d_in[15]};
    k_ingest<<<6377, 256, 0, stream>>>(t0, t1, t2, t3, t4, x, xp, CS, smallC, dstA, cnt);

    k_scan<<<1, 256, 0, stream>>>(cnt, rowptr, cursor, dinv);
    k_fill<<<(EE + 255) / 256, 256, 0, stream>>>(srcA, dstA, cursor, cols, vals, dinv);

    auto gx = [](int nbm, int nbn) { return 8 * ((nbm + 7) / 8) * nbn; };

    // input GEMM: S1 = gelu(xp @ winT^T + b_in)  [MPAD,256], K=128
    k_gemm<128, 64, 1, 0, 0><<<gx(79, 4), 256, 0, stream>>>(xp, xp, xp, xp, winT, binC, S1, nullptr,
                                                            nullptr, nullptr, nullptr, 128, 256, 0, 79, 4);

    // ---- layer 0: prop chain (bf16) then batched GEMM ----
    k_propw<<<2500, 256, 0, stream>>>(S1, 256, 1, rowptr, cols, vals, dinv, S2);
    k_propw<<<2500, 256, 0, stream>>>(S2, 256, 1, rowptr, cols, vals, dinv, S3);
    k_propw<<<2500, 256, 0, stream>>>(S3, 256, 1, rowptr, cols, vals, dinv, S4);
    k_gemm<128, 64, 0, 0, 1><<<dim3(gx(79, 4), 4), 256, 0, stream>>>(S1, S2, S3, S4, w0T, mb0C, concat, nullptr,
                                                                     nullptr, nullptr, nullptr, 256, 1024, 0, 79, 4);
    k_ln_gelu<<<NN, 256, 0, stream>>>(concat, lngC, lnbC, bufA);

    // ---- layers 1,2: merged GEMM (EPI2: z -> fp8 Zb) + fp8 prop chain (R13) ----
    for (int L = 0; L < 2; L++) {
        const u16* WT = w12T + (size_t)L * 1024 * 1024;
        const u16* BB = mb12C + L * 1024;
        k_gemm<128, 64, 0, 2, 0><<<gx(79, 16), 256, 0, stream>>>(bufA, bufA, bufA, bufA, WT, BB, concat, Zb,
                                                                 nullptr, nullptr, nullptr, 1024, 0, 0, 79, 16);
        k_propf8<<<7500, 256, 0, stream>>>(Zb, 768, 3, rowptr, cols, vals, dinv, concat, BB + 256, 256, Y2);
        k_propf8<<<5000, 256, 0, stream>>>(Y2, 512, 2, rowptr, cols, vals, dinv, concat, BB + 512, 512, Y3);
        k_propf8<<<2500, 256, 0, stream>>>(Y3, 256, 1, rowptr, cols, vals, dinv, concat, BB + 768, 768, nullptr);
        k_ln_gelu<<<NN, 256, 0, stream>>>(concat, lngC + (L + 1) * 1024, lnbC + (L + 1) * 1024, bufA);
    }

    // ---- final MLP: w1 GEMM, then fused w2-GEMM + head dot ----
    k_gemm<64, 64, 1, 0, 0><<<gx(158, 4), 256, 0, stream>>>(bufA, bufA, bufA, bufA, w1T, b1C, S1, nullptr,
                                                            nullptr, nullptr, nullptr, 1024, 256, 0, 158, 4);
    k_gemm<64, 128, 0, 3, 0><<<gx(158, 1), 256, 0, stream>>>(S1, S1, S1, S1, w2T, b2C, nullptr, nullptr,
                                                             w3C, b3C, out, 256, 0, 0, 158, 1);
}